// Round 1
// baseline (3011.599 us; speedup 1.0000x reference)
//
#include <hip/hip_runtime.h>
#include <math.h>

// Problem constants
#define NB 512      // batch
#define NT 64       // encoder seq len
#define ND 512      // input dim
#define NH 256      // hidden dim
#define NA 256      // attention dim
#define NC 96       // num classes
#define NSTEPS 26

// ---------------------------------------------------------------------------
// Generic fp32 NT GEMM:  C[M,N] = A[M,K] @ W[N,K].T + bias[N]
// 64x64 block tile, 256 threads, 4x4 per thread, K tile 16.
// M, N must be multiples of 64; K multiple of 16. ldc == N.
// ---------------------------------------------------------------------------
__device__ __forceinline__ void gemm_body(const float* __restrict__ A,
                                          const float* __restrict__ W,
                                          const float* __restrict__ bias,
                                          float* __restrict__ C,
                                          int K, int N, int bm, int bn)
{
    __shared__ float As[16][68];
    __shared__ float Bs[16][68];
    const int tid = threadIdx.x;
    const int tx = tid & 15;   // 0..15 (n micro)
    const int ty = tid >> 4;   // 0..15 (m micro)
    const int lk = tid & 15;   // k within tile for loads
    const int lr = tid >> 4;   // row group for loads

    float acc[4][4];
#pragma unroll
    for (int i = 0; i < 4; ++i)
#pragma unroll
        for (int j = 0; j < 4; ++j) acc[i][j] = 0.f;

    const float* Ab = A + (long long)bm * K;
    const float* Wb = W + (long long)bn * K;

    for (int k0 = 0; k0 < K; k0 += 16) {
#pragma unroll
        for (int i = 0; i < 4; ++i) {
            As[lk][lr + i * 16] = Ab[(long long)(lr + i * 16) * K + k0 + lk];
            Bs[lk][lr + i * 16] = Wb[(long long)(lr + i * 16) * K + k0 + lk];
        }
        __syncthreads();
#pragma unroll
        for (int kk = 0; kk < 16; ++kk) {
            const float4 av = *(const float4*)&As[kk][ty * 4];
            const float4 bv = *(const float4*)&Bs[kk][tx * 4];
            const float a[4] = {av.x, av.y, av.z, av.w};
            const float b[4] = {bv.x, bv.y, bv.z, bv.w};
#pragma unroll
            for (int i = 0; i < 4; ++i)
#pragma unroll
                for (int j = 0; j < 4; ++j)
                    acc[i][j] = fmaf(a[i], b[j], acc[i][j]);
        }
        __syncthreads();
    }

#pragma unroll
    for (int i = 0; i < 4; ++i) {
        const int row = bm + ty * 4 + i;
        const int col = bn + tx * 4;
        float4 o;
        o.x = acc[i][0] + bias[col + 0];
        o.y = acc[i][1] + bias[col + 1];
        o.z = acc[i][2] + bias[col + 2];
        o.w = acc[i][3] + bias[col + 3];
        *(float4*)&C[(long long)row * N + col] = o;
    }
}

__global__ __launch_bounds__(256) void k_gemm(const float* __restrict__ A,
                                              const float* __restrict__ W,
                                              const float* __restrict__ bias,
                                              float* __restrict__ C,
                                              int K, int N)
{
    gemm_body(A, W, bias, C, K, N, blockIdx.x * 64, blockIdx.y * 64);
}

// gi = g2 @ Wih.T + bih  (K=768)   [blockIdx.z == 0]
// gh = h  @ Whh.T + bhh  (K=256)   [blockIdx.z == 1]
__global__ __launch_bounds__(256) void k_gru_gemm(const float* __restrict__ g2,
                                                  const float* __restrict__ Wih,
                                                  const float* __restrict__ bih,
                                                  float* __restrict__ gi,
                                                  const float* __restrict__ h,
                                                  const float* __restrict__ Whh,
                                                  const float* __restrict__ bhh,
                                                  float* __restrict__ gh)
{
    const float* A;
    const float* W;
    const float* bias;
    float* C;
    int K;
    if (blockIdx.z == 0) { A = g2; W = Wih; bias = bih; C = gi; K = 768; }
    else                 { A = h;  W = Whh; bias = bhh; C = gh; K = 256; }
    gemm_body(A, W, bias, C, K, 768, blockIdx.x * 64, blockIdx.y * 64);
}

// ---------------------------------------------------------------------------
// Attention step: per block b:
//   v[t]   = bw + sum_a Ww[a] * tanh(sProj[b,a] + xProj[b,t,a])
//   alpha  = softmax_t(v)
//   ctx[d] = sum_t alpha[t] * img[b,t,d]
//   g2[b]  = [emb[y_b], ctx]
// ---------------------------------------------------------------------------
__global__ __launch_bounds__(256) void k_att(const float* __restrict__ img,
                                             const float* __restrict__ xProj,
                                             const float* __restrict__ sProj,
                                             const float* __restrict__ Ww,
                                             const float* __restrict__ bw,
                                             const float* __restrict__ emb,
                                             const int* __restrict__ label,
                                             int step,
                                             float* __restrict__ g2)
{
    const int b = blockIdx.x;
    const int tid = threadIdx.x;
    const int lane = tid & 63;
    const int wave = tid >> 6;    // 0..3

    __shared__ float sS[NA];
    __shared__ float wwS[NA];
    __shared__ float vS[NT];
    __shared__ float alphaS[NT];

    sS[tid] = sProj[b * NA + tid];
    wwS[tid] = Ww[tid];
    __syncthreads();

    const float bw0 = bw[0];
    // each wave handles 16 t values
#pragma unroll 1
    for (int tt = 0; tt < 16; ++tt) {
        const int t = wave * 16 + tt;
        const float* xp = xProj + ((long long)b * NT + t) * NA;
        float s = 0.f;
#pragma unroll
        for (int c = 0; c < 4; ++c) {
            const int a = lane + c * 64;
            s += wwS[a] * tanhf(sS[a] + xp[a]);
        }
#pragma unroll
        for (int off = 32; off > 0; off >>= 1) s += __shfl_down(s, off);
        if (lane == 0) vS[t] = s + bw0;
    }
    __syncthreads();

    if (wave == 0) {
        float v = vS[lane];
        float m = v;
#pragma unroll
        for (int off = 32; off > 0; off >>= 1) m = fmaxf(m, __shfl_xor(m, off));
        float e = expf(v - m);
        float ssum = e;
#pragma unroll
        for (int off = 32; off > 0; off >>= 1) ssum += __shfl_xor(ssum, off);
        alphaS[lane] = e / ssum;
    }
    __syncthreads();

    // ctx: thread handles d = tid and d = tid + 256
    float c0 = 0.f, c1 = 0.f;
    const float* imgb = img + (long long)b * NT * ND;
#pragma unroll 4
    for (int t = 0; t < NT; ++t) {
        const float al = alphaS[t];
        c0 = fmaf(al, imgb[t * ND + tid], c0);
        c1 = fmaf(al, imgb[t * ND + 256 + tid], c1);
    }

    const int y = (step == 0) ? 0 : label[b * NSTEPS + step];
    float* g2b = g2 + (long long)b * 768;
    g2b[tid]       = emb[y * NA + tid];
    g2b[256 + tid] = c0;
    g2b[512 + tid] = c1;
}

// ---------------------------------------------------------------------------
// Gate + h update + FC output. One block per b, 256 threads.
// ---------------------------------------------------------------------------
__global__ __launch_bounds__(256) void k_gate(const float* __restrict__ gi,
                                              const float* __restrict__ gh,
                                              float* __restrict__ h,
                                              const float* __restrict__ WfcT,
                                              const float* __restrict__ bfc,
                                              float* __restrict__ out,
                                              int step)
{
    const int b = blockIdx.x;
    const int j = threadIdx.x;
    __shared__ float hS[NH];

    const long long o3 = (long long)b * 768;
    const float gir = gi[o3 + j];
    const float giz = gi[o3 + 256 + j];
    const float gin = gi[o3 + 512 + j];
    const float ghr = gh[o3 + j];
    const float ghz = gh[o3 + 256 + j];
    const float ghn = gh[o3 + 512 + j];

    const float r = 1.f / (1.f + expf(-(gir + ghr)));
    const float z = 1.f / (1.f + expf(-(giz + ghz)));
    const float n = tanhf(fmaf(r, ghn, gin));
    const float hp = h[b * NH + j];
    const float hn = (1.f - z) * n + z * hp;
    h[b * NH + j] = hn;
    hS[j] = hn;
    __syncthreads();

    if (j < NC) {
        float acc = bfc[j];
#pragma unroll 4
        for (int k = 0; k < NH; ++k)
            acc = fmaf(hS[k], WfcT[k * NC + j], acc);
        out[((long long)b * NSTEPS + step) * NC + j] = acc;
    }
}

// Transpose Wfc [96,256] -> WfcT [256,96]
__global__ __launch_bounds__(128) void k_prep(const float* __restrict__ Wfc,
                                              float* __restrict__ WfcT)
{
    const int k = blockIdx.x;     // 0..255
    const int c = threadIdx.x;    // 0..127
    if (c < NC) WfcT[k * NC + c] = Wfc[c * NH + k];
}

// ---------------------------------------------------------------------------
extern "C" void kernel_launch(void* const* d_in, const int* in_sizes, int n_in,
                              void* d_out, int out_size, void* d_ws, size_t ws_size,
                              hipStream_t stream)
{
    const float* img   = (const float*)d_in[0];   // [B,T,D]
    const int*   label = (const int*)d_in[1];     // [B,STEPS]
    const float* Wx    = (const float*)d_in[2];   // [A,D]
    const float* bx    = (const float*)d_in[3];   // [A]
    const float* Ws    = (const float*)d_in[4];   // [A,H]
    const float* bs    = (const float*)d_in[5];   // [A]
    const float* Ww    = (const float*)d_in[6];   // [1,A]
    const float* bw    = (const float*)d_in[7];   // [1]
    const float* emb   = (const float*)d_in[8];   // [C+1,A]
    const float* Wih   = (const float*)d_in[9];   // [3H, D+A] = [768,768]
    const float* bih   = (const float*)d_in[10];  // [768]
    const float* Whh   = (const float*)d_in[11];  // [3H, H] = [768,256]
    const float* bhh   = (const float*)d_in[12];  // [768]
    const float* Wfc   = (const float*)d_in[13];  // [C,H]
    const float* bfc   = (const float*)d_in[14];  // [C]
    float* out = (float*)d_out;                   // [B,STEPS,C]

    float* ws = (float*)d_ws;
    float* xProj = ws;                          // 8388608
    float* g2    = xProj + (size_t)NB * NT * NA;  // 393216
    float* gi    = g2 + (size_t)NB * 768;         // 393216
    float* gh    = gi + (size_t)NB * 768;         // 393216
    float* h     = gh + (size_t)NB * 768;         // 131072
    float* sProj = h + (size_t)NB * NH;           // 131072
    float* WfcT  = sProj + (size_t)NB * NA;       // 24576

    // h0 = 0
    hipMemsetAsync(h, 0, (size_t)NB * NH * sizeof(float), stream);
    k_prep<<<dim3(NH), dim3(128), 0, stream>>>(Wfc, WfcT);

    // xProj = img @ Wx.T + bx : M=B*T=32768, N=256, K=512
    k_gemm<<<dim3((NB * NT) / 64, NA / 64), dim3(256), 0, stream>>>(
        img, Wx, bx, xProj, ND, NA);

    for (int step = 0; step < NSTEPS; ++step) {
        // sProj = h @ Ws.T + bs : M=512, N=256, K=256
        k_gemm<<<dim3(NB / 64, NA / 64), dim3(256), 0, stream>>>(
            h, Ws, bs, sProj, NH, NA);

        k_att<<<dim3(NB), dim3(256), 0, stream>>>(
            img, xProj, sProj, Ww, bw, emb, label, step, g2);

        // gi (z=0) and gh (z=1): M=512, N=768
        k_gru_gemm<<<dim3(NB / 64, 768 / 64, 2), dim3(256), 0, stream>>>(
            g2, Wih, bih, gi, h, Whh, bhh, gh);

        k_gate<<<dim3(NB), dim3(256), 0, stream>>>(
            gi, gh, h, WfcT, bfc, out, step);
    }
}

// Round 2
// 2138.798 us; speedup vs baseline: 1.4081x; 1.4081x over previous
//
#include <hip/hip_runtime.h>
#include <math.h>

#define NB 512
#define NT 64
#define ND 512
#define NH 256
#define NA 256
#define NC 96
#define NSTEPS 26

typedef __attribute__((ext_vector_type(8))) short short8;
typedef __attribute__((ext_vector_type(4))) float f32x4;

static __device__ __forceinline__ unsigned short f2bf(float f) {
    unsigned int u = __float_as_uint(f);
    unsigned int r = (u + 0x7FFFu + ((u >> 16) & 1u)) >> 16;
    return (unsigned short)r;
}
static __device__ __forceinline__ float bf2f(unsigned short u) {
    return __uint_as_float(((unsigned int)u) << 16);
}

// ---------------------------------------------------------------------------
// One-time prep: pack weights to bf16, build fused GRU weight matrix,
// packed bias, transposed Ws/Wfc, init sProj = bs.
// grid: 4096 x 256  (idx covers 1,048,576)
// ---------------------------------------------------------------------------
__global__ __launch_bounds__(256) void k_prep(
    const float* __restrict__ Wx, const float* __restrict__ Ws,
    const float* __restrict__ Wfc, const float* __restrict__ Wih,
    const float* __restrict__ Whh, const float* __restrict__ bih,
    const float* __restrict__ bhh, const float* __restrict__ bs,
    unsigned short* __restrict__ Wxbf, unsigned short* __restrict__ WsT,
    unsigned short* __restrict__ WfcT, unsigned short* __restrict__ Wp,
    float* __restrict__ biasp, float* __restrict__ sProj)
{
    const int idx = blockIdx.x * 256 + threadIdx.x;

    // Wp [1024 x 1024]: rows 0-255 r:[Wih_r|Whh_r], 256-511 z:[Wih_z|Whh_z],
    // 512-767 n_i:[Wih_n|0], 768-1023 n_h:[0|Whh_n]
    {
        const int n = idx >> 10, k = idx & 1023;
        float val;
        if (n < 512)      val = (k < 768) ? Wih[n * 768 + k] : Whh[n * 256 + (k - 768)];
        else if (n < 768) val = (k < 768) ? Wih[n * 768 + k] : 0.f;
        else              val = (k >= 768) ? Whh[(n - 256) * 256 + (k - 768)] : 0.f;
        Wp[idx] = f2bf(val);
    }
    if (idx < 131072) Wxbf[idx] = f2bf(Wx[idx]);
    if (idx < 131072) sProj[idx] = bs[idx & 255];               // h0=0 -> sProj=bs
    if (idx < 65536) {
        const int k = idx >> 8, j = idx & 255;
        WsT[idx] = f2bf(Ws[j * 256 + k]);                       // WsT[k][j]
    }
    if (idx < 24576) {
        const int k = idx / 96, c = idx % 96;
        WfcT[idx] = f2bf(Wfc[c * 256 + k]);                     // WfcT[k][c]
    }
    if (idx < 1024) {
        const int j = idx & 255;
        float v;
        if (idx < 256)      v = bih[j] + bhh[j];
        else if (idx < 512) v = bih[256 + j] + bhh[256 + j];
        else if (idx < 768) v = bih[512 + j];
        else                v = bhh[512 + j];
        biasp[idx] = v;
    }
}

// ---------------------------------------------------------------------------
// xProj = img @ Wx.T + bx, output bf16.  M=32768 N=256 K=512.
// 64x64 tile, 256 threads (4 waves), MFMA 16x16x32 bf16.
// img fp32 is converted to bf16 during LDS staging.
// ---------------------------------------------------------------------------
__global__ __launch_bounds__(256) void k_xproj(
    const float* __restrict__ img, const unsigned short* __restrict__ Wxbf,
    const float* __restrict__ bx, unsigned short* __restrict__ xProjbf)
{
    __shared__ unsigned short As[64][40];
    __shared__ unsigned short Bs[64][40];

    const int tid = threadIdx.x;
    const int lane = tid & 63;
    const int w = tid >> 6;           // wave 0..3
    const int l15 = lane & 15;
    const int q = lane >> 4;          // 0..3
    const int bm = blockIdx.x * 64;
    const int bn = blockIdx.y * 64;

    const int srow = tid >> 2;        // 0..63
    const int sc0 = (tid & 3) * 8;    // 0,8,16,24

    f32x4 acc[4];
#pragma unroll
    for (int i = 0; i < 4; ++i) acc[i] = (f32x4){0.f, 0.f, 0.f, 0.f};

    for (int k0 = 0; k0 < ND; k0 += 32) {
        // stage A (fp32 -> bf16)
        const float* ap = img + (size_t)(bm + srow) * ND + k0 + sc0;
        const float4 v0 = *(const float4*)ap;
        const float4 v1 = *(const float4*)(ap + 4);
        short8 av;
        av[0] = (short)f2bf(v0.x); av[1] = (short)f2bf(v0.y);
        av[2] = (short)f2bf(v0.z); av[3] = (short)f2bf(v0.w);
        av[4] = (short)f2bf(v1.x); av[5] = (short)f2bf(v1.y);
        av[6] = (short)f2bf(v1.z); av[7] = (short)f2bf(v1.w);
        *(short8*)&As[srow][sc0] = av;
        // stage B (already bf16)
        *(short8*)&Bs[srow][sc0] =
            *(const short8*)(Wxbf + (size_t)(bn + srow) * ND + k0 + sc0);
        __syncthreads();

        const short8 bf = *(const short8*)&Bs[w * 16 + l15][q * 8];
#pragma unroll
        for (int mt = 0; mt < 4; ++mt) {
            const short8 af = *(const short8*)&As[mt * 16 + l15][q * 8];
            acc[mt] = __builtin_amdgcn_mfma_f32_16x16x32_bf16(af, bf, acc[mt], 0, 0, 0);
        }
        __syncthreads();
    }

#pragma unroll
    for (int mt = 0; mt < 4; ++mt) {
        const int col = bn + w * 16 + l15;
        const float bxv = bx[col];
#pragma unroll
        for (int r = 0; r < 4; ++r) {
            const int row = bm + mt * 16 + q * 4 + r;
            xProjbf[(size_t)row * NA + col] = f2bf(acc[mt][r] + bxv);
        }
    }
}

// ---------------------------------------------------------------------------
// GRU fused GEMM: gsum[512,1024] = Amat[512,1024]bf16 @ Wp[1024,1024]bf16.T + biasp
// 32x64 tile, 256 threads (4 waves), grid (16,16) = 256 blocks.
// ---------------------------------------------------------------------------
__global__ __launch_bounds__(256) void k_gru(
    const unsigned short* __restrict__ Amat, const unsigned short* __restrict__ Wp,
    const float* __restrict__ biasp, float* __restrict__ gsum)
{
    __shared__ unsigned short As[32][40];
    __shared__ unsigned short Bs[64][40];

    const int tid = threadIdx.x;
    const int lane = tid & 63;
    const int w = tid >> 6;
    const int l15 = lane & 15;
    const int q = lane >> 4;
    const int bm = blockIdx.x * 32;
    const int bn = blockIdx.y * 64;

    const int srow = tid >> 2;
    const int sc0 = (tid & 3) * 8;

    f32x4 acc[2];
    acc[0] = (f32x4){0.f, 0.f, 0.f, 0.f};
    acc[1] = (f32x4){0.f, 0.f, 0.f, 0.f};

    for (int k0 = 0; k0 < 1024; k0 += 32) {
        *(short8*)&Bs[srow][sc0] =
            *(const short8*)(Wp + (size_t)(bn + srow) * 1024 + k0 + sc0);
        if (tid < 128)
            *(short8*)&As[srow][sc0] =
                *(const short8*)(Amat + (size_t)(bm + srow) * 1024 + k0 + sc0);
        __syncthreads();

        const short8 bf = *(const short8*)&Bs[w * 16 + l15][q * 8];
#pragma unroll
        for (int mt = 0; mt < 2; ++mt) {
            const short8 af = *(const short8*)&As[mt * 16 + l15][q * 8];
            acc[mt] = __builtin_amdgcn_mfma_f32_16x16x32_bf16(af, bf, acc[mt], 0, 0, 0);
        }
        __syncthreads();
    }

#pragma unroll
    for (int mt = 0; mt < 2; ++mt) {
        const int col = bn + w * 16 + l15;
        const float bv = biasp[col];
#pragma unroll
        for (int r = 0; r < 4; ++r) {
            const int row = bm + mt * 16 + q * 4 + r;
            gsum[(size_t)row * 1024 + col] = acc[mt][r] + bv;
        }
    }
}

// ---------------------------------------------------------------------------
// Attention: v = Ww . tanh(sProj + xProj) + bw ; alpha = softmax(v);
// ctx = alpha @ img ; Amat[b] = [bf16(emb[y]) | bf16(ctx) | (h cols untouched)]
// ---------------------------------------------------------------------------
__global__ __launch_bounds__(256) void k_att(
    const float* __restrict__ img, const unsigned short* __restrict__ xProjbf,
    const float* __restrict__ sProj, const float* __restrict__ Ww,
    const float* __restrict__ bw, const float* __restrict__ emb,
    const int* __restrict__ label, int step, unsigned short* __restrict__ Amat)
{
    const int b = blockIdx.x;
    const int tid = threadIdx.x;
    const int lane = tid & 63;
    const int w = tid >> 6;

    __shared__ float sS[NA];
    __shared__ float wwS[NA];
    __shared__ float vS[NT];
    __shared__ float alphaS[NT];

    sS[tid] = sProj[b * NA + tid];
    wwS[tid] = Ww[tid];
    __syncthreads();

    const float bw0 = bw[0];
#pragma unroll 1
    for (int tt = 0; tt < 16; ++tt) {
        const int t = w * 16 + tt;
        const ushort4 x4 = *(const ushort4*)(xProjbf + ((size_t)(b * NT + t)) * NA + lane * 4);
        float s = wwS[lane * 4 + 0] * tanhf(sS[lane * 4 + 0] + bf2f(x4.x));
        s += wwS[lane * 4 + 1] * tanhf(sS[lane * 4 + 1] + bf2f(x4.y));
        s += wwS[lane * 4 + 2] * tanhf(sS[lane * 4 + 2] + bf2f(x4.z));
        s += wwS[lane * 4 + 3] * tanhf(sS[lane * 4 + 3] + bf2f(x4.w));
#pragma unroll
        for (int off = 32; off > 0; off >>= 1) s += __shfl_xor(s, off);
        if (lane == 0) vS[t] = s + bw0;
    }
    __syncthreads();

    if (w == 0) {
        float v = vS[lane];
        float m = v;
#pragma unroll
        for (int off = 32; off > 0; off >>= 1) m = fmaxf(m, __shfl_xor(m, off));
        float e = expf(v - m);
        float ssum = e;
#pragma unroll
        for (int off = 32; off > 0; off >>= 1) ssum += __shfl_xor(ssum, off);
        alphaS[lane] = e / ssum;
    }
    __syncthreads();

    // ctx: thread handles d0 = 2*tid, 2*tid+1
    float c0 = 0.f, c1 = 0.f;
    const float* imgb = img + (size_t)b * NT * ND + 2 * tid;
#pragma unroll 4
    for (int t = 0; t < NT; ++t) {
        const float al = alphaS[t];
        const float2 iv = *(const float2*)(imgb + (size_t)t * ND);
        c0 = fmaf(al, iv.x, c0);
        c1 = fmaf(al, iv.y, c1);
    }

    const int y = (step == 0) ? 0 : label[b * NSTEPS + step];
    unsigned short* Ab = Amat + (size_t)b * 1024;
    Ab[tid] = f2bf(emb[y * NA + tid]);
    ushort2 cx;
    cx.x = f2bf(c0);
    cx.y = f2bf(c1);
    *(ushort2*)(Ab + 256 + 2 * tid) = cx;
}

// ---------------------------------------------------------------------------
// Gate + h update + FC out + sProj for next step.
// gsum layout per row b: [0:256)=r_pre [256:512)=z_pre [512:768)=gin [768:1024)=ghn
// ---------------------------------------------------------------------------
__global__ __launch_bounds__(256) void k_gate(
    const float* __restrict__ gsum, float* __restrict__ h,
    unsigned short* __restrict__ Amat, const unsigned short* __restrict__ WfcT,
    const float* __restrict__ bfc, const unsigned short* __restrict__ WsT,
    const float* __restrict__ bs, float* __restrict__ sProj,
    float* __restrict__ out, int step)
{
    const int b = blockIdx.x;
    const int j = threadIdx.x;
    __shared__ float hS[NH];

    const size_t o = (size_t)b * 1024;
    const float r_pre = gsum[o + j];
    const float z_pre = gsum[o + 256 + j];
    const float gin = gsum[o + 512 + j];
    const float ghn = gsum[o + 768 + j];

    const float r = 1.f / (1.f + expf(-r_pre));
    const float z = 1.f / (1.f + expf(-z_pre));
    const float n = tanhf(fmaf(r, ghn, gin));
    const float hp = h[b * NH + j];
    const float hn = (1.f - z) * n + z * hp;
    h[b * NH + j] = hn;
    hS[j] = hn;
    Amat[(size_t)b * 1024 + 768 + j] = f2bf(hn);
    __syncthreads();

    // FC out
    if (j < NC) {
        float acc = bfc[j];
#pragma unroll 4
        for (int k = 0; k < NH; ++k)
            acc = fmaf(hS[k], bf2f(WfcT[k * NC + j]), acc);
        out[((size_t)b * NSTEPS + step) * NC + j] = acc;
    }

    // sProj for next step: sProj[b,j] = bs[j] + sum_k h[k] * Ws[j,k]
    float sp = bs[j];
#pragma unroll 4
    for (int k = 0; k < NH; ++k)
        sp = fmaf(hS[k], bf2f(WsT[k * NA + j]), sp);
    sProj[b * NA + j] = sp;
}

// ---------------------------------------------------------------------------
extern "C" void kernel_launch(void* const* d_in, const int* in_sizes, int n_in,
                              void* d_out, int out_size, void* d_ws, size_t ws_size,
                              hipStream_t stream)
{
    const float* img   = (const float*)d_in[0];
    const int*   label = (const int*)d_in[1];
    const float* Wx    = (const float*)d_in[2];
    const float* bx    = (const float*)d_in[3];
    const float* Ws    = (const float*)d_in[4];
    const float* bs    = (const float*)d_in[5];
    const float* Ww    = (const float*)d_in[6];
    const float* bw    = (const float*)d_in[7];
    const float* emb   = (const float*)d_in[8];
    const float* Wih   = (const float*)d_in[9];
    const float* bih   = (const float*)d_in[10];
    const float* Whh   = (const float*)d_in[11];
    const float* bhh   = (const float*)d_in[12];
    const float* Wfc   = (const float*)d_in[13];
    const float* bfc   = (const float*)d_in[14];
    float* out = (float*)d_out;

    float* ws = (float*)d_ws;
    float* gsum  = ws;                                  // 524288 f
    float* h     = gsum + 524288;                       // 131072 f
    float* sProj = h + 131072;                          // 131072 f
    float* biasp = sProj + 131072;                      // 1024 f
    unsigned short* xProjbf = (unsigned short*)(biasp + 1024);   // 8388608 s
    unsigned short* Amat = xProjbf + 8388608;           // 524288 s
    unsigned short* Wp   = Amat + 524288;               // 1048576 s
    unsigned short* Wxbf = Wp + 1048576;                // 131072 s
    unsigned short* WsT  = Wxbf + 131072;               // 65536 s
    unsigned short* WfcT = WsT + 65536;                 // 24576 s

    hipMemsetAsync(h, 0, (size_t)NB * NH * sizeof(float), stream);
    hipMemsetAsync(Amat, 0, (size_t)NB * 1024 * sizeof(unsigned short), stream);

    k_prep<<<dim3(4096), dim3(256), 0, stream>>>(
        Wx, Ws, Wfc, Wih, Whh, bih, bhh, bs,
        Wxbf, WsT, WfcT, Wp, biasp, sProj);

    k_xproj<<<dim3((NB * NT) / 64, NA / 64), dim3(256), 0, stream>>>(
        img, Wxbf, bx, xProjbf);

    for (int step = 0; step < NSTEPS; ++step) {
        k_att<<<dim3(NB), dim3(256), 0, stream>>>(
            img, xProjbf, sProj, Ww, bw, emb, label, step, Amat);

        k_gru<<<dim3(512 / 32, 1024 / 64), dim3(256), 0, stream>>>(
            Amat, Wp, biasp, gsum);

        k_gate<<<dim3(NB), dim3(256), 0, stream>>>(
            gsum, h, Amat, WfcT, bfc, WsT, bs, sProj, out, step);
    }
}

// Round 3
// 1987.496 us; speedup vs baseline: 1.5153x; 1.0761x over previous
//
#include <hip/hip_runtime.h>
#include <math.h>

#define NB 512
#define NT 64
#define ND 512
#define NH 256
#define NA 256
#define NC 96
#define NSTEPS 26

typedef __attribute__((ext_vector_type(8))) short short8;
typedef __attribute__((ext_vector_type(4))) float f32x4;

static __device__ __forceinline__ unsigned short f2bf(float f) {
    unsigned int u = __float_as_uint(f);
    unsigned int r = (u + 0x7FFFu + ((u >> 16) & 1u)) >> 16;
    return (unsigned short)r;
}
static __device__ __forceinline__ float bf2f(unsigned short u) {
    return __uint_as_float(((unsigned int)u) << 16);
}

// ---------------------------------------------------------------------------
// Prep: pack weights to bf16, build fused GRU weight Wp, packed bias,
// transposed Ws/Wfc. grid 4096 x 256.
// ---------------------------------------------------------------------------
__global__ __launch_bounds__(256) void k_prep(
    const float* __restrict__ Wx, const float* __restrict__ Ws,
    const float* __restrict__ Wfc, const float* __restrict__ Wih,
    const float* __restrict__ Whh, const float* __restrict__ bih,
    const float* __restrict__ bhh,
    unsigned short* __restrict__ Wxbf, unsigned short* __restrict__ WsT,
    unsigned short* __restrict__ WfcT, unsigned short* __restrict__ Wp,
    float* __restrict__ biasp)
{
    const int idx = blockIdx.x * 256 + threadIdx.x;

    // Wp [1024 x 1024]: rows 0-255 r:[Wih_r|Whh_r], 256-511 z:[Wih_z|Whh_z],
    // 512-767 n_i:[Wih_n|0], 768-1023 n_h:[0|Whh_n]
    {
        const int n = idx >> 10, k = idx & 1023;
        float val;
        if (n < 512)      val = (k < 768) ? Wih[n * 768 + k] : Whh[n * 256 + (k - 768)];
        else if (n < 768) val = (k < 768) ? Wih[n * 768 + k] : 0.f;
        else              val = (k >= 768) ? Whh[(n - 256) * 256 + (k - 768)] : 0.f;
        Wp[idx] = f2bf(val);
    }
    if (idx < 131072) Wxbf[idx] = f2bf(Wx[idx]);
    if (idx < 65536) {
        const int k = idx >> 8, j = idx & 255;
        WsT[idx] = f2bf(Ws[j * 256 + k]);          // WsT[k][j]
    }
    if (idx < 24576) {
        const int k = idx / 96, c = idx % 96;
        WfcT[idx] = f2bf(Wfc[c * 256 + k]);        // WfcT[k][c]
    }
    if (idx < 1024) {
        const int j = idx & 255;
        float v;
        if (idx < 256)      v = bih[j] + bhh[j];
        else if (idx < 512) v = bih[256 + j] + bhh[256 + j];
        else if (idx < 768) v = bih[512 + j];
        else                v = bhh[512 + j];
        biasp[idx] = v;
    }
}

// img fp32 -> bf16. 8 elems/thread, grid 8192 x 256.
__global__ __launch_bounds__(256) void k_convert(
    const float* __restrict__ img, unsigned short* __restrict__ imgbf)
{
    const int idx = (blockIdx.x * 256 + threadIdx.x) * 8;
    const float4 v0 = *(const float4*)(img + idx);
    const float4 v1 = *(const float4*)(img + idx + 4);
    short8 o;
    o[0] = (short)f2bf(v0.x); o[1] = (short)f2bf(v0.y);
    o[2] = (short)f2bf(v0.z); o[3] = (short)f2bf(v0.w);
    o[4] = (short)f2bf(v1.x); o[5] = (short)f2bf(v1.y);
    o[6] = (short)f2bf(v1.z); o[7] = (short)f2bf(v1.w);
    *(short8*)(imgbf + idx) = o;
}

// ---------------------------------------------------------------------------
// xProj = img @ Wx.T + bx -> bf16. M=32768 N=256 K=512. 64x64 tile, MFMA.
// ---------------------------------------------------------------------------
__global__ __launch_bounds__(256) void k_xproj(
    const float* __restrict__ img, const unsigned short* __restrict__ imgbf,
    int use_bf, const unsigned short* __restrict__ Wxbf,
    const float* __restrict__ bx, unsigned short* __restrict__ xProjbf)
{
    __shared__ unsigned short As[64][40];
    __shared__ unsigned short Bs[64][40];

    const int tid = threadIdx.x;
    const int lane = tid & 63;
    const int w = tid >> 6;
    const int l15 = lane & 15;
    const int q = lane >> 4;
    const int bm = blockIdx.x * 64;
    const int bn = blockIdx.y * 64;

    const int srow = tid >> 2;
    const int sc0 = (tid & 3) * 8;

    f32x4 acc[4];
#pragma unroll
    for (int i = 0; i < 4; ++i) acc[i] = (f32x4){0.f, 0.f, 0.f, 0.f};

    for (int k0 = 0; k0 < ND; k0 += 32) {
        if (use_bf) {
            *(short8*)&As[srow][sc0] =
                *(const short8*)(imgbf + (size_t)(bm + srow) * ND + k0 + sc0);
        } else {
            const float* ap = img + (size_t)(bm + srow) * ND + k0 + sc0;
            const float4 v0 = *(const float4*)ap;
            const float4 v1 = *(const float4*)(ap + 4);
            short8 av;
            av[0] = (short)f2bf(v0.x); av[1] = (short)f2bf(v0.y);
            av[2] = (short)f2bf(v0.z); av[3] = (short)f2bf(v0.w);
            av[4] = (short)f2bf(v1.x); av[5] = (short)f2bf(v1.y);
            av[6] = (short)f2bf(v1.z); av[7] = (short)f2bf(v1.w);
            *(short8*)&As[srow][sc0] = av;
        }
        *(short8*)&Bs[srow][sc0] =
            *(const short8*)(Wxbf + (size_t)(bn + srow) * ND + k0 + sc0);
        __syncthreads();

        const short8 bf = *(const short8*)&Bs[w * 16 + l15][q * 8];
#pragma unroll
        for (int mt = 0; mt < 4; ++mt) {
            const short8 af = *(const short8*)&As[mt * 16 + l15][q * 8];
            acc[mt] = __builtin_amdgcn_mfma_f32_16x16x32_bf16(af, bf, acc[mt], 0, 0, 0);
        }
        __syncthreads();
    }

#pragma unroll
    for (int mt = 0; mt < 4; ++mt) {
        const int col = bn + w * 16 + l15;
        const float bxv = bx[col];
#pragma unroll
        for (int r = 0; r < 4; ++r) {
            const int row = bm + mt * 16 + q * 4 + r;
            xProjbf[(size_t)row * NA + col] = f2bf(acc[mt][r] + bxv);
        }
    }
}

// ---------------------------------------------------------------------------
// GRU GEMM: gsum[512,1024] = Amat[512,1024] @ Wp[1024,1024].T + biasp
// ---------------------------------------------------------------------------
__global__ __launch_bounds__(256) void k_gru(
    const unsigned short* __restrict__ Amat, const unsigned short* __restrict__ Wp,
    const float* __restrict__ biasp, float* __restrict__ gsum)
{
    __shared__ unsigned short As[32][40];
    __shared__ unsigned short Bs[64][40];

    const int tid = threadIdx.x;
    const int lane = tid & 63;
    const int w = tid >> 6;
    const int l15 = lane & 15;
    const int q = lane >> 4;
    const int bm = blockIdx.x * 32;
    const int bn = blockIdx.y * 64;

    const int srow = tid >> 2;
    const int sc0 = (tid & 3) * 8;

    f32x4 acc[2];
    acc[0] = (f32x4){0.f, 0.f, 0.f, 0.f};
    acc[1] = (f32x4){0.f, 0.f, 0.f, 0.f};

    for (int k0 = 0; k0 < 1024; k0 += 32) {
        *(short8*)&Bs[srow][sc0] =
            *(const short8*)(Wp + (size_t)(bn + srow) * 1024 + k0 + sc0);
        if (tid < 128)
            *(short8*)&As[srow][sc0] =
                *(const short8*)(Amat + (size_t)(bm + srow) * 1024 + k0 + sc0);
        __syncthreads();

        const short8 bf = *(const short8*)&Bs[w * 16 + l15][q * 8];
#pragma unroll
        for (int mt = 0; mt < 2; ++mt) {
            const short8 af = *(const short8*)&As[mt * 16 + l15][q * 8];
            acc[mt] = __builtin_amdgcn_mfma_f32_16x16x32_bf16(af, bf, acc[mt], 0, 0, 0);
        }
        __syncthreads();
    }

#pragma unroll
    for (int mt = 0; mt < 2; ++mt) {
        const int col = bn + w * 16 + l15;
        const float bv = biasp[col];
#pragma unroll
        for (int r = 0; r < 4; ++r) {
            const int row = bm + mt * 16 + q * 4 + r;
            gsum[(size_t)row * 1024 + col] = acc[mt][r] + bv;
        }
    }
}

// ---------------------------------------------------------------------------
// Fused per-step tail: gate (h update) + FC out + sProj (LDS only) +
// attention for step+1 -> Amat.  step == -1: h=0 path (initial attention).
// ---------------------------------------------------------------------------
__global__ __launch_bounds__(256) void k_step(
    const float* __restrict__ gsum, float* __restrict__ h,
    unsigned short* __restrict__ Amat,
    const unsigned short* __restrict__ WfcT, const float* __restrict__ bfc,
    const unsigned short* __restrict__ WsT, const float* __restrict__ bs,
    float* __restrict__ out,
    const unsigned short* __restrict__ imgbf, const float* __restrict__ imgf,
    int use_bf, const unsigned short* __restrict__ xProjbf,
    const float* __restrict__ Ww, const float* __restrict__ bw,
    const float* __restrict__ emb, const int* __restrict__ label, int step)
{
    const int b = blockIdx.x;
    const int j = threadIdx.x;
    const int lane = j & 63;
    const int w = j >> 6;

    __shared__ float hS[NH];
    __shared__ float sS[NA];
    __shared__ float wwS[NA];
    __shared__ float vS[NT];
    __shared__ float alphaS[NT];

    float hn = 0.f;
    if (step >= 0) {
        const size_t o = (size_t)b * 1024;
        const float r_pre = gsum[o + j];
        const float z_pre = gsum[o + 256 + j];
        const float gin = gsum[o + 512 + j];
        const float ghn = gsum[o + 768 + j];
        const float r = 1.f / (1.f + expf(-r_pre));
        const float z = 1.f / (1.f + expf(-z_pre));
        const float n = tanhf(fmaf(r, ghn, gin));
        const float hp = h[b * NH + j];
        hn = (1.f - z) * n + z * hp;
    }
    h[b * NH + j] = hn;
    hS[j] = hn;
    wwS[j] = Ww[j];
    __syncthreads();

    // FC out
    if (step >= 0 && j < NC) {
        float acc = bfc[j];
#pragma unroll 4
        for (int k = 0; k < NH; ++k)
            acc = fmaf(hS[k], bf2f(WfcT[k * NC + j]), acc);
        out[((size_t)b * NSTEPS + step) * NC + j] = acc;
    }

    const int att_step = step + 1;
    if (att_step >= NSTEPS) return;

    // sProj into LDS
    float sp = bs[j];
    if (step >= 0) {
#pragma unroll 4
        for (int k = 0; k < NH; ++k)
            sp = fmaf(hS[k], bf2f(WsT[k * NA + j]), sp);
    }
    sS[j] = sp;
    Amat[(size_t)b * 1024 + 768 + j] = f2bf(hn);
    __syncthreads();

    // attention scores
    const float bw0 = bw[0];
#pragma unroll 1
    for (int tt = 0; tt < 16; ++tt) {
        const int t = w * 16 + tt;
        const ushort4 x4 = *(const ushort4*)(xProjbf + ((size_t)(b * NT + t)) * NA + lane * 4);
        float s = wwS[lane * 4 + 0] * tanhf(sS[lane * 4 + 0] + bf2f(x4.x));
        s += wwS[lane * 4 + 1] * tanhf(sS[lane * 4 + 1] + bf2f(x4.y));
        s += wwS[lane * 4 + 2] * tanhf(sS[lane * 4 + 2] + bf2f(x4.z));
        s += wwS[lane * 4 + 3] * tanhf(sS[lane * 4 + 3] + bf2f(x4.w));
#pragma unroll
        for (int off = 32; off > 0; off >>= 1) s += __shfl_xor(s, off);
        if (lane == 0) vS[t] = s + bw0;
    }
    __syncthreads();

    if (w == 0) {
        float v = vS[lane];
        float m = v;
#pragma unroll
        for (int off = 32; off > 0; off >>= 1) m = fmaxf(m, __shfl_xor(m, off));
        float e = expf(v - m);
        float ssum = e;
#pragma unroll
        for (int off = 32; off > 0; off >>= 1) ssum += __shfl_xor(ssum, off);
        alphaS[lane] = e / ssum;
    }
    __syncthreads();

    // ctx
    float c0 = 0.f, c1 = 0.f;
    if (use_bf) {
        const unsigned short* ib = imgbf + (size_t)b * NT * ND + 2 * j;
#pragma unroll 4
        for (int t = 0; t < NT; ++t) {
            const float al = alphaS[t];
            const ushort2 iv = *(const ushort2*)(ib + (size_t)t * ND);
            c0 = fmaf(al, bf2f(iv.x), c0);
            c1 = fmaf(al, bf2f(iv.y), c1);
        }
    } else {
        const float* ib = imgf + (size_t)b * NT * ND + 2 * j;
#pragma unroll 4
        for (int t = 0; t < NT; ++t) {
            const float al = alphaS[t];
            const float2 iv = *(const float2*)(ib + (size_t)t * ND);
            c0 = fmaf(al, iv.x, c0);
            c1 = fmaf(al, iv.y, c1);
        }
    }

    const int y = (att_step == 0) ? 0 : label[b * NSTEPS + att_step];
    unsigned short* Ab = Amat + (size_t)b * 1024;
    Ab[j] = f2bf(emb[y * NA + j]);
    ushort2 cx;
    cx.x = f2bf(c0);
    cx.y = f2bf(c1);
    *(ushort2*)(Ab + 256 + 2 * j) = cx;
}

// ---------------------------------------------------------------------------
extern "C" void kernel_launch(void* const* d_in, const int* in_sizes, int n_in,
                              void* d_out, int out_size, void* d_ws, size_t ws_size,
                              hipStream_t stream)
{
    const float* img   = (const float*)d_in[0];
    const int*   label = (const int*)d_in[1];
    const float* Wx    = (const float*)d_in[2];
    const float* bx    = (const float*)d_in[3];
    const float* Ws    = (const float*)d_in[4];
    const float* bs    = (const float*)d_in[5];
    const float* Ww    = (const float*)d_in[6];
    const float* bw    = (const float*)d_in[7];
    const float* emb   = (const float*)d_in[8];
    const float* Wih   = (const float*)d_in[9];
    const float* bih   = (const float*)d_in[10];
    const float* Whh   = (const float*)d_in[11];
    const float* bhh   = (const float*)d_in[12];
    const float* Wfc   = (const float*)d_in[13];
    const float* bfc   = (const float*)d_in[14];
    float* out = (float*)d_out;

    float* ws = (float*)d_ws;
    float* gsum  = ws;                                     // 524288 f
    float* h     = gsum + 524288;                          // 131072 f
    float* biasp = h + 131072;                             // 1024 f
    unsigned short* xProjbf = (unsigned short*)(biasp + 1024);  // 8388608 s
    unsigned short* Amat = xProjbf + 8388608;              // 524288 s
    unsigned short* Wp   = Amat + 524288;                  // 1048576 s
    unsigned short* Wxbf = Wp + 1048576;                   // 131072 s
    unsigned short* WsT  = Wxbf + 131072;                  // 65536 s
    unsigned short* WfcT = WsT + 65536;                    // 24576 s
    unsigned short* imgbf = WfcT + 24576;                  // 16777216 s (optional)

    const size_t need_bf = (size_t)((char*)(imgbf + 16777216) - (char*)d_ws);
    const int use_bf = (ws_size >= need_bf) ? 1 : 0;       // ws_size constant across calls

    k_prep<<<dim3(4096), dim3(256), 0, stream>>>(
        Wx, Ws, Wfc, Wih, Whh, bih, bhh, Wxbf, WsT, WfcT, Wp, biasp);

    if (use_bf)
        k_convert<<<dim3(8192), dim3(256), 0, stream>>>(img, imgbf);

    k_xproj<<<dim3((NB * NT) / 64, NA / 64), dim3(256), 0, stream>>>(
        img, imgbf, use_bf, Wxbf, bx, xProjbf);

    // initial attention (h = 0, sProj = bs, y = 0)
    k_step<<<dim3(NB), dim3(256), 0, stream>>>(
        gsum, h, Amat, WfcT, bfc, WsT, bs, out,
        imgbf, img, use_bf, xProjbf, Ww, bw, emb, label, -1);

    for (int step = 0; step < NSTEPS; ++step) {
        k_gru<<<dim3(512 / 32, 1024 / 64), dim3(256), 0, stream>>>(
            Amat, Wp, biasp, gsum);

        k_step<<<dim3(NB), dim3(256), 0, stream>>>(
            gsum, h, Amat, WfcT, bfc, WsT, bs, out,
            imgbf, img, use_bf, xProjbf, Ww, bw, emb, label, step);
    }
}

// Round 4
// 1269.154 us; speedup vs baseline: 2.3729x; 1.5660x over previous
//
#include <hip/hip_runtime.h>
#include <math.h>

#define NB 512
#define NT 64
#define ND 512
#define NH 256
#define NA 256
#define NC 96
#define NSTEPS 26
#define NGRU 1152   // 1024 gru cols + 96 fc (padded to 128)

typedef __attribute__((ext_vector_type(8))) short short8;
typedef __attribute__((ext_vector_type(4))) float f32x4;

static __device__ __forceinline__ unsigned short f2bf(float f) {
    unsigned int u = __float_as_uint(f);
    unsigned int r = (u + 0x7FFFu + ((u >> 16) & 1u)) >> 16;
    return (unsigned short)r;
}
static __device__ __forceinline__ float bf2f(unsigned short u) {
    return __uint_as_float(((unsigned int)u) << 16);
}

// ---------------------------------------------------------------------------
// Prep: pack weights bf16; build fused weight Wp [1152 x 1024]:
//   rows 0-255   r:  [Wih_r | Whh_r]
//   rows 256-511 z:  [Wih_z | Whh_z]
//   rows 512-767 ni: [Wih_n | 0]
//   rows 768-1023 nh:[0     | Whh_n]
//   rows 1024-1119 fc:[0    | Wfc ]   (bias = bfc)
//   rows 1120-1151   zero pad
// grid 4608 x 256 (covers 1,179,648)
// ---------------------------------------------------------------------------
__global__ __launch_bounds__(256) void k_prep(
    const float* __restrict__ Wx, const float* __restrict__ Ws,
    const float* __restrict__ Wfc, const float* __restrict__ Wih,
    const float* __restrict__ Whh, const float* __restrict__ bih,
    const float* __restrict__ bhh, const float* __restrict__ bfc,
    unsigned short* __restrict__ Wxbf, unsigned short* __restrict__ WsT,
    unsigned short* __restrict__ WfcT, unsigned short* __restrict__ Wp,
    float* __restrict__ biasp)
{
    const int idx = blockIdx.x * 256 + threadIdx.x;
    if (idx < NGRU * 1024) {
        const int n = idx >> 10, k = idx & 1023;
        float val;
        if (n < 512)       val = (k < 768) ? Wih[n * 768 + k] : Whh[n * 256 + (k - 768)];
        else if (n < 768)  val = (k < 768) ? Wih[n * 768 + k] : 0.f;
        else if (n < 1024) val = (k >= 768) ? Whh[(n - 256) * 256 + (k - 768)] : 0.f;
        else if (n < 1120) val = (k >= 768) ? Wfc[(n - 1024) * 256 + (k - 768)] : 0.f;
        else               val = 0.f;
        Wp[idx] = f2bf(val);
    }
    if (idx < 131072) Wxbf[idx] = f2bf(Wx[idx]);
    if (idx < 65536) {
        const int k = idx >> 8, j = idx & 255;
        WsT[idx] = f2bf(Ws[j * 256 + k]);          // WsT[k][j]
    }
    if (idx < 24576) {
        const int k = idx / 96, c = idx % 96;
        WfcT[idx] = f2bf(Wfc[c * 256 + k]);        // WfcT[k][c]
    }
    if (idx < NGRU) {
        float v;
        const int j = idx & 255;
        if (idx < 256)       v = bih[j] + bhh[j];
        else if (idx < 512)  v = bih[256 + j] + bhh[256 + j];
        else if (idx < 768)  v = bih[512 + j];
        else if (idx < 1024) v = bhh[512 + j];
        else if (idx < 1120) v = bfc[idx - 1024];
        else                 v = 0.f;
        biasp[idx] = v;
    }
}

// img fp32 -> bf16. grid 8192 x 256.
__global__ __launch_bounds__(256) void k_convert(
    const float* __restrict__ img, unsigned short* __restrict__ imgbf)
{
    const int idx = (blockIdx.x * 256 + threadIdx.x) * 8;
    const float4 v0 = *(const float4*)(img + idx);
    const float4 v1 = *(const float4*)(img + idx + 4);
    short8 o;
    o[0] = (short)f2bf(v0.x); o[1] = (short)f2bf(v0.y);
    o[2] = (short)f2bf(v0.z); o[3] = (short)f2bf(v0.w);
    o[4] = (short)f2bf(v1.x); o[5] = (short)f2bf(v1.y);
    o[6] = (short)f2bf(v1.z); o[7] = (short)f2bf(v1.w);
    *(short8*)(imgbf + idx) = o;
}

// ---------------------------------------------------------------------------
// xProj = img @ Wx.T + bx -> bf16. M=32768 N=256 K=512.
// ---------------------------------------------------------------------------
__global__ __launch_bounds__(256) void k_xproj(
    const float* __restrict__ img, const unsigned short* __restrict__ imgbf,
    int use_bf, const unsigned short* __restrict__ Wxbf,
    const float* __restrict__ bx, unsigned short* __restrict__ xProjbf)
{
    __shared__ unsigned short As[64][40];
    __shared__ unsigned short Bs[64][40];

    const int tid = threadIdx.x;
    const int lane = tid & 63;
    const int w = tid >> 6;
    const int l15 = lane & 15;
    const int q = lane >> 4;
    const int bm = blockIdx.x * 64;
    const int bn = blockIdx.y * 64;
    const int srow = tid >> 2;
    const int sc0 = (tid & 3) * 8;

    f32x4 acc[4];
#pragma unroll
    for (int i = 0; i < 4; ++i) acc[i] = (f32x4){0.f, 0.f, 0.f, 0.f};

    for (int k0 = 0; k0 < ND; k0 += 32) {
        if (use_bf) {
            *(short8*)&As[srow][sc0] =
                *(const short8*)(imgbf + (size_t)(bm + srow) * ND + k0 + sc0);
        } else {
            const float* ap = img + (size_t)(bm + srow) * ND + k0 + sc0;
            const float4 v0 = *(const float4*)ap;
            const float4 v1 = *(const float4*)(ap + 4);
            short8 av;
            av[0] = (short)f2bf(v0.x); av[1] = (short)f2bf(v0.y);
            av[2] = (short)f2bf(v0.z); av[3] = (short)f2bf(v0.w);
            av[4] = (short)f2bf(v1.x); av[5] = (short)f2bf(v1.y);
            av[6] = (short)f2bf(v1.z); av[7] = (short)f2bf(v1.w);
            *(short8*)&As[srow][sc0] = av;
        }
        *(short8*)&Bs[srow][sc0] =
            *(const short8*)(Wxbf + (size_t)(bn + srow) * ND + k0 + sc0);
        __syncthreads();

        const short8 bf = *(const short8*)&Bs[w * 16 + l15][q * 8];
#pragma unroll
        for (int mt = 0; mt < 4; ++mt) {
            const short8 af = *(const short8*)&As[mt * 16 + l15][q * 8];
            acc[mt] = __builtin_amdgcn_mfma_f32_16x16x32_bf16(af, bf, acc[mt], 0, 0, 0);
        }
        __syncthreads();
    }

#pragma unroll
    for (int mt = 0; mt < 4; ++mt) {
        const int col = bn + w * 16 + l15;
        const float bxv = bx[col];
#pragma unroll
        for (int r = 0; r < 4; ++r) {
            const int row = bm + mt * 16 + q * 4 + r;
            xProjbf[(size_t)row * NA + col] = f2bf(acc[mt][r] + bxv);
        }
    }
}

// ---------------------------------------------------------------------------
// GRU+FC GEMM: gsum[512,1152] = Amat[512,1024] @ Wp[1152,1024].T + biasp
// cols 1024..1119 are out[b, out_step, :] (FC of h_{out_step}); written when
// out_step >= 0. grid (16,18).
// ---------------------------------------------------------------------------
__global__ __launch_bounds__(256) void k_gru(
    const unsigned short* __restrict__ Amat, const unsigned short* __restrict__ Wp,
    const float* __restrict__ biasp, float* __restrict__ gsum,
    float* __restrict__ out, int out_step)
{
    __shared__ unsigned short As[32][40];
    __shared__ unsigned short Bs[64][40];

    const int tid = threadIdx.x;
    const int lane = tid & 63;
    const int w = tid >> 6;
    const int l15 = lane & 15;
    const int q = lane >> 4;
    const int bm = blockIdx.x * 32;
    const int bn = blockIdx.y * 64;
    const int srow = tid >> 2;
    const int sc0 = (tid & 3) * 8;

    f32x4 acc[2];
    acc[0] = (f32x4){0.f, 0.f, 0.f, 0.f};
    acc[1] = (f32x4){0.f, 0.f, 0.f, 0.f};

    for (int k0 = 0; k0 < 1024; k0 += 32) {
        *(short8*)&Bs[srow][sc0] =
            *(const short8*)(Wp + (size_t)(bn + srow) * 1024 + k0 + sc0);
        if (tid < 128)
            *(short8*)&As[srow][sc0] =
                *(const short8*)(Amat + (size_t)(bm + srow) * 1024 + k0 + sc0);
        __syncthreads();

        const short8 bf = *(const short8*)&Bs[w * 16 + l15][q * 8];
#pragma unroll
        for (int mt = 0; mt < 2; ++mt) {
            const short8 af = *(const short8*)&As[mt * 16 + l15][q * 8];
            acc[mt] = __builtin_amdgcn_mfma_f32_16x16x32_bf16(af, bf, acc[mt], 0, 0, 0);
        }
        __syncthreads();
    }

#pragma unroll
    for (int mt = 0; mt < 2; ++mt) {
        const int col = bn + w * 16 + l15;
        const float bv = biasp[col];
#pragma unroll
        for (int r = 0; r < 4; ++r) {
            const int row = bm + mt * 16 + q * 4 + r;
            const float v = acc[mt][r] + bv;
            gsum[(size_t)row * NGRU + col] = v;
            if (out_step >= 0 && col >= 1024 && col < 1120)
                out[((size_t)row * NSTEPS + out_step) * NC + (col - 1024)] = v;
        }
    }
}

// ---------------------------------------------------------------------------
// Fused per-step tail: gate (h update) + sProj + attention(step+1) -> Amat.
// step == -1: h=0 init path.  FC output handled by k_gru / k_fc.
// ---------------------------------------------------------------------------
__global__ __launch_bounds__(256) void k_step(
    const float* __restrict__ gsum, float* __restrict__ h,
    unsigned short* __restrict__ Amat,
    const unsigned short* __restrict__ WsT, const float* __restrict__ bs,
    const unsigned short* __restrict__ imgbf, const float* __restrict__ imgf,
    int use_bf, const unsigned short* __restrict__ xProjbf,
    const float* __restrict__ Ww, const float* __restrict__ bw,
    const float* __restrict__ emb, const int* __restrict__ label, int step)
{
    const int b = blockIdx.x;
    const int j = threadIdx.x;
    const int lane = j & 63;
    const int w = j >> 6;

    __shared__ float hS[NH];
    __shared__ float sS[NA];
    __shared__ float wwS[NA];
    __shared__ float vS[NT];
    __shared__ float alphaS[NT];
    __shared__ float ctxS[4][512];

    // ---- gate ----
    float hn = 0.f;
    if (step >= 0) {
        const size_t o = (size_t)b * NGRU;
        const float r_pre = gsum[o + j];
        const float z_pre = gsum[o + 256 + j];
        const float gin = gsum[o + 512 + j];
        const float ghn = gsum[o + 768 + j];
        const float r = 1.f / (1.f + expf(-r_pre));
        const float z = 1.f / (1.f + expf(-z_pre));
        const float n = tanhf(fmaf(r, ghn, gin));
        const float hp = h[b * NH + j];
        hn = (1.f - z) * n + z * hp;
    }
    h[b * NH + j] = hn;
    hS[j] = hn;
    wwS[j] = Ww[j];
    Amat[(size_t)b * 1024 + 768 + j] = f2bf(hn);
    __syncthreads();

    const int att_step = step + 1;
    if (att_step >= NSTEPS) return;

    // ---- sProj (LDS only) ----
    float sp = bs[j];
    if (step >= 0) {
#pragma unroll 8
        for (int k = 0; k < NH; ++k)
            sp = fmaf(hS[k], bf2f(WsT[k * NA + j]), sp);
    }
    sS[j] = sp;
    __syncthreads();

    // ---- scores: half-wave per t, lane covers 8 a's held in registers ----
    const int a0 = (lane & 31) * 8;
    float ss[8], ww[8];
    {
        const float4 s0 = *(const float4*)&sS[a0];
        const float4 s1 = *(const float4*)&sS[a0 + 4];
        const float4 w0 = *(const float4*)&wwS[a0];
        const float4 w1 = *(const float4*)&wwS[a0 + 4];
        ss[0] = s0.x; ss[1] = s0.y; ss[2] = s0.z; ss[3] = s0.w;
        ss[4] = s1.x; ss[5] = s1.y; ss[6] = s1.z; ss[7] = s1.w;
        ww[0] = w0.x; ww[1] = w0.y; ww[2] = w0.z; ww[3] = w0.w;
        ww[4] = w1.x; ww[5] = w1.y; ww[6] = w1.z; ww[7] = w1.w;
    }
    const float bw0 = bw[0];
#pragma unroll 2
    for (int p = 0; p < 8; ++p) {
        const int t = w * 16 + p * 2 + (lane >> 5);
        const short8 x8 = *(const short8*)(xProjbf + ((size_t)(b * NT + t)) * NA + a0);
        float s = 0.f;
#pragma unroll
        for (int i = 0; i < 8; ++i)
            s += ww[i] * tanhf(ss[i] + bf2f((unsigned short)x8[i]));
#pragma unroll
        for (int off = 16; off > 0; off >>= 1) s += __shfl_xor(s, off);
        if ((lane & 31) == 0) vS[t] = s + bw0;
    }
    __syncthreads();

    // ---- softmax over 64 t (wave 0) ----
    if (w == 0) {
        float v = vS[lane];
        float m = v;
#pragma unroll
        for (int off = 32; off > 0; off >>= 1) m = fmaxf(m, __shfl_xor(m, off));
        float e = expf(v - m);
        float ssum = e;
#pragma unroll
        for (int off = 32; off > 0; off >>= 1) ssum += __shfl_xor(ssum, off);
        alphaS[lane] = e / ssum;
    }
    __syncthreads();

    // ---- ctx: lane covers 8 contiguous d, wave covers 16 t, LDS reduce ----
    const int d0 = lane * 8;
    float c[8];
#pragma unroll
    for (int i = 0; i < 8; ++i) c[i] = 0.f;

    if (use_bf) {
        const unsigned short* ib = imgbf + (size_t)b * NT * ND + d0;
#pragma unroll 4
        for (int i = 0; i < 16; ++i) {
            const int t = w + 4 * i;
            const float al = alphaS[t];
            const short8 v = *(const short8*)(ib + (size_t)t * ND);
#pragma unroll
            for (int k = 0; k < 8; ++k)
                c[k] = fmaf(al, bf2f((unsigned short)v[k]), c[k]);
        }
    } else {
        const float* ib = imgf + (size_t)b * NT * ND + d0;
#pragma unroll 4
        for (int i = 0; i < 16; ++i) {
            const int t = w + 4 * i;
            const float al = alphaS[t];
            const float4 v0 = *(const float4*)(ib + (size_t)t * ND);
            const float4 v1 = *(const float4*)(ib + (size_t)t * ND + 4);
            c[0] = fmaf(al, v0.x, c[0]); c[1] = fmaf(al, v0.y, c[1]);
            c[2] = fmaf(al, v0.z, c[2]); c[3] = fmaf(al, v0.w, c[3]);
            c[4] = fmaf(al, v1.x, c[4]); c[5] = fmaf(al, v1.y, c[5]);
            c[6] = fmaf(al, v1.z, c[6]); c[7] = fmaf(al, v1.w, c[7]);
        }
    }
    *(f32x4*)&ctxS[w][d0] = (f32x4){c[0], c[1], c[2], c[3]};
    *(f32x4*)&ctxS[w][d0 + 4] = (f32x4){c[4], c[5], c[6], c[7]};
    __syncthreads();

    float cx0 = ctxS[0][2 * j] + ctxS[1][2 * j] + ctxS[2][2 * j] + ctxS[3][2 * j];
    float cx1 = ctxS[0][2 * j + 1] + ctxS[1][2 * j + 1] + ctxS[2][2 * j + 1] + ctxS[3][2 * j + 1];

    const int y = (att_step == 0) ? 0 : label[b * NSTEPS + att_step];
    unsigned short* Ab = Amat + (size_t)b * 1024;
    Ab[j] = f2bf(emb[y * NA + j]);
    ushort2 cx;
    cx.x = f2bf(cx0);
    cx.y = f2bf(cx1);
    *(ushort2*)(Ab + 256 + 2 * j) = cx;
}

// Final-step FC: out[b,25,:] = h @ Wfc.T + bfc
__global__ __launch_bounds__(128) void k_fc(
    const float* __restrict__ h, const unsigned short* __restrict__ WfcT,
    const float* __restrict__ bfc, float* __restrict__ out)
{
    const int b = blockIdx.x;
    const int j = threadIdx.x;
    __shared__ float hS[NH];
    hS[j] = h[b * NH + j];
    hS[128 + j] = h[b * NH + 128 + j];
    __syncthreads();
    if (j < NC) {
        float acc = bfc[j];
#pragma unroll 8
        for (int k = 0; k < NH; ++k)
            acc = fmaf(hS[k], bf2f(WfcT[k * NC + j]), acc);
        out[((size_t)b * NSTEPS + (NSTEPS - 1)) * NC + j] = acc;
    }
}

// ---------------------------------------------------------------------------
extern "C" void kernel_launch(void* const* d_in, const int* in_sizes, int n_in,
                              void* d_out, int out_size, void* d_ws, size_t ws_size,
                              hipStream_t stream)
{
    const float* img   = (const float*)d_in[0];
    const int*   label = (const int*)d_in[1];
    const float* Wx    = (const float*)d_in[2];
    const float* bx    = (const float*)d_in[3];
    const float* Ws    = (const float*)d_in[4];
    const float* bs    = (const float*)d_in[5];
    const float* Ww    = (const float*)d_in[6];
    const float* bw    = (const float*)d_in[7];
    const float* emb   = (const float*)d_in[8];
    const float* Wih   = (const float*)d_in[9];
    const float* bih   = (const float*)d_in[10];
    const float* Whh   = (const float*)d_in[11];
    const float* bhh   = (const float*)d_in[12];
    const float* Wfc   = (const float*)d_in[13];
    const float* bfc   = (const float*)d_in[14];
    float* out = (float*)d_out;

    float* ws = (float*)d_ws;
    float* gsum  = ws;                                       // 589824 f
    float* h     = gsum + 589824;                            // 131072 f
    float* biasp = h + 131072;                               // 1280 f
    unsigned short* xProjbf = (unsigned short*)(biasp + 1280);   // 8388608 s
    unsigned short* Amat = xProjbf + 8388608;                // 524288 s
    unsigned short* Wp   = Amat + 524288;                    // 1179648 s
    unsigned short* Wxbf = Wp + 1179648;                     // 131072 s
    unsigned short* WsT  = Wxbf + 131072;                    // 65536 s
    unsigned short* WfcT = WsT + 65536;                      // 24576 s
    unsigned short* imgbf = WfcT + 24576;                    // 16777216 s (optional)

    const size_t need_bf = (size_t)((char*)(imgbf + 16777216) - (char*)d_ws);
    const int use_bf = (ws_size >= need_bf) ? 1 : 0;

    k_prep<<<dim3(4608), dim3(256), 0, stream>>>(
        Wx, Ws, Wfc, Wih, Whh, bih, bhh, bfc,
        Wxbf, WsT, WfcT, Wp, biasp);

    if (use_bf)
        k_convert<<<dim3(8192), dim3(256), 0, stream>>>(img, imgbf);

    k_xproj<<<dim3((NB * NT) / 64, NA / 64), dim3(256), 0, stream>>>(
        img, imgbf, use_bf, Wxbf, bx, xProjbf);

    // initial attention (h=0, sProj=bs, y=0); also zero-inits h and Amat h-section
    k_step<<<dim3(NB), dim3(256), 0, stream>>>(
        gsum, h, Amat, WsT, bs, imgbf, img, use_bf, xProjbf,
        Ww, bw, emb, label, -1);

    for (int step = 0; step < NSTEPS; ++step) {
        k_gru<<<dim3(16, 18), dim3(256), 0, stream>>>(
            Amat, Wp, biasp, gsum, out, step - 1);

        k_step<<<dim3(NB), dim3(256), 0, stream>>>(
            gsum, h, Amat, WsT, bs, imgbf, img, use_bf, xProjbf,
            Ww, bw, emb, label, step);
    }

    k_fc<<<dim3(NB), dim3(128), 0, stream>>>(h, WfcT, bfc, out);
}

// Round 5
// 1177.917 us; speedup vs baseline: 2.5567x; 1.0775x over previous
//
#include <hip/hip_runtime.h>
#include <math.h>

#define NB 512
#define NT 64
#define ND 512
#define NH 256
#define NA 256
#define NC 96
#define NSTEPS 26
#define NGRU 1152   // 1024 interleaved gru cols + 96 fc + 32 pad

typedef __attribute__((ext_vector_type(8))) short short8;
typedef __attribute__((ext_vector_type(4))) float f32x4;

static __device__ __forceinline__ unsigned short f2bf(float f) {
    unsigned int u = __float_as_uint(f);
    unsigned int r = (u + 0x7FFFu + ((u >> 16) & 1u)) >> 16;
    return (unsigned short)r;
}
static __device__ __forceinline__ float bf2f(unsigned short u) {
    return __uint_as_float(((unsigned int)u) << 16);
}

// ---------------------------------------------------------------------------
// Prep. Wp [1152 x 1024], rows INTERLEAVED for gate-in-epilogue:
//   row 4j+0 : r  gate col j : [Wih_r(j)   | Whh_r(j)  ]
//   row 4j+1 : z  gate col j : [Wih_z(j)   | Whh_z(j)  ]
//   row 4j+2 : ni gate col j : [Wih_n(j)   | 0         ]
//   row 4j+3 : nh gate col j : [0          | Whh_n(j)  ]
//   rows 1024-1119 : FC      : [0          | Wfc       ]
//   rows 1120-1151 : zero pad
// biasp matches row order. grid 4608 x 256.
// ---------------------------------------------------------------------------
__global__ __launch_bounds__(256) void k_prep(
    const float* __restrict__ Wx, const float* __restrict__ Ws,
    const float* __restrict__ Wfc, const float* __restrict__ Wih,
    const float* __restrict__ Whh, const float* __restrict__ bih,
    const float* __restrict__ bhh, const float* __restrict__ bfc,
    unsigned short* __restrict__ Wxbf, unsigned short* __restrict__ Wsbf,
    unsigned short* __restrict__ WfcT, unsigned short* __restrict__ Wp,
    float* __restrict__ biasp)
{
    const int idx = blockIdx.x * 256 + threadIdx.x;
    if (idx < NGRU * 1024) {
        const int n = idx >> 10, k = idx & 1023;
        float val = 0.f;
        if (n < 1024) {
            const int j = n >> 2, g = n & 3;
            if (g == 0)      val = (k < 768) ? Wih[j * 768 + k] : Whh[j * 256 + (k - 768)];
            else if (g == 1) val = (k < 768) ? Wih[(256 + j) * 768 + k] : Whh[(256 + j) * 256 + (k - 768)];
            else if (g == 2) val = (k < 768) ? Wih[(512 + j) * 768 + k] : 0.f;
            else             val = (k >= 768) ? Whh[(512 + j) * 256 + (k - 768)] : 0.f;
        } else if (n < 1120) {
            val = (k >= 768) ? Wfc[(n - 1024) * 256 + (k - 768)] : 0.f;
        }
        Wp[idx] = f2bf(val);
    }
    if (idx < 131072) Wxbf[idx] = f2bf(Wx[idx]);
    if (idx < 65536)  Wsbf[idx] = f2bf(Ws[idx]);        // row-major [j][k]
    if (idx < 24576) {
        const int k = idx / 96, c = idx % 96;
        WfcT[idx] = f2bf(Wfc[c * 256 + k]);             // WfcT[k][c]
    }
    if (idx < NGRU) {
        float v = 0.f;
        if (idx < 1024) {
            const int j = idx >> 2, g = idx & 3;
            if (g == 0)      v = bih[j] + bhh[j];
            else if (g == 1) v = bih[256 + j] + bhh[256 + j];
            else if (g == 2) v = bih[512 + j];
            else             v = bhh[512 + j];
        } else if (idx < 1120) {
            v = bfc[idx - 1024];
        }
        biasp[idx] = v;
    }
}

// img fp32 -> bf16. grid 8192 x 256.
__global__ __launch_bounds__(256) void k_convert(
    const float* __restrict__ img, unsigned short* __restrict__ imgbf)
{
    const int idx = (blockIdx.x * 256 + threadIdx.x) * 8;
    const float4 v0 = *(const float4*)(img + idx);
    const float4 v1 = *(const float4*)(img + idx + 4);
    short8 o;
    o[0] = (short)f2bf(v0.x); o[1] = (short)f2bf(v0.y);
    o[2] = (short)f2bf(v0.z); o[3] = (short)f2bf(v0.w);
    o[4] = (short)f2bf(v1.x); o[5] = (short)f2bf(v1.y);
    o[6] = (short)f2bf(v1.z); o[7] = (short)f2bf(v1.w);
    *(short8*)(imgbf + idx) = o;
}

// ---------------------------------------------------------------------------
// xProj = img @ Wx.T + bx -> bf16. M=32768 N=256 K=512.
// ---------------------------------------------------------------------------
__global__ __launch_bounds__(256) void k_xproj(
    const float* __restrict__ img, const unsigned short* __restrict__ imgbf,
    int use_bf, const unsigned short* __restrict__ Wxbf,
    const float* __restrict__ bx, unsigned short* __restrict__ xProjbf)
{
    __shared__ unsigned short As[64][40];
    __shared__ unsigned short Bs[64][40];

    const int tid = threadIdx.x;
    const int lane = tid & 63;
    const int w = tid >> 6;
    const int l15 = lane & 15;
    const int q = lane >> 4;
    const int bm = blockIdx.x * 64;
    const int bn = blockIdx.y * 64;
    const int srow = tid >> 2;
    const int sc0 = (tid & 3) * 8;

    f32x4 acc[4];
#pragma unroll
    for (int i = 0; i < 4; ++i) acc[i] = (f32x4){0.f, 0.f, 0.f, 0.f};

    for (int k0 = 0; k0 < ND; k0 += 32) {
        if (use_bf) {
            *(short8*)&As[srow][sc0] =
                *(const short8*)(imgbf + (size_t)(bm + srow) * ND + k0 + sc0);
        } else {
            const float* ap = img + (size_t)(bm + srow) * ND + k0 + sc0;
            const float4 v0 = *(const float4*)ap;
            const float4 v1 = *(const float4*)(ap + 4);
            short8 av;
            av[0] = (short)f2bf(v0.x); av[1] = (short)f2bf(v0.y);
            av[2] = (short)f2bf(v0.z); av[3] = (short)f2bf(v0.w);
            av[4] = (short)f2bf(v1.x); av[5] = (short)f2bf(v1.y);
            av[6] = (short)f2bf(v1.z); av[7] = (short)f2bf(v1.w);
            *(short8*)&As[srow][sc0] = av;
        }
        *(short8*)&Bs[srow][sc0] =
            *(const short8*)(Wxbf + (size_t)(bn + srow) * ND + k0 + sc0);
        __syncthreads();

        const short8 bf = *(const short8*)&Bs[w * 16 + l15][q * 8];
#pragma unroll
        for (int mt = 0; mt < 4; ++mt) {
            const short8 af = *(const short8*)&As[mt * 16 + l15][q * 8];
            acc[mt] = __builtin_amdgcn_mfma_f32_16x16x32_bf16(af, bf, acc[mt], 0, 0, 0);
        }
        __syncthreads();
    }

#pragma unroll
    for (int mt = 0; mt < 4; ++mt) {
        const int col = bn + w * 16 + l15;
        const float bxv = bx[col];
#pragma unroll
        for (int r = 0; r < 4; ++r) {
            const int row = bm + mt * 16 + q * 4 + r;
            xProjbf[(size_t)row * NA + col] = f2bf(acc[mt][r] + bxv);
        }
    }
}

// ---------------------------------------------------------------------------
// GRU GEMM + fused gate epilogue.
// Ain [512,1024] bf16 = [emb | ctx | h_s].  Computes pre-activations for the
// interleaved Wp, then applies the GRU gate in-block: writes h (f32) and
// Aout h-slot (bf16).  FC tiles (by>=16) write out[:, out_step].
// grid (16, 18), 256 threads.
// ---------------------------------------------------------------------------
__global__ __launch_bounds__(256) void k_gru(
    const unsigned short* __restrict__ Ain, unsigned short* __restrict__ Aout,
    const unsigned short* __restrict__ Wp, const float* __restrict__ biasp,
    float* __restrict__ h, float* __restrict__ out, int out_step)
{
    __shared__ unsigned short As[32][40];
    __shared__ unsigned short Bs[64][40];
    __shared__ float CS[32][65];

    const int tid = threadIdx.x;
    const int lane = tid & 63;
    const int w = tid >> 6;
    const int l15 = lane & 15;
    const int q = lane >> 4;
    const int bm = blockIdx.x * 32;
    const int bn = blockIdx.y * 64;
    const int srow = tid >> 2;
    const int sc0 = (tid & 3) * 8;

    f32x4 acc[2];
    acc[0] = (f32x4){0.f, 0.f, 0.f, 0.f};
    acc[1] = (f32x4){0.f, 0.f, 0.f, 0.f};

    for (int k0 = 0; k0 < 1024; k0 += 32) {
        *(short8*)&Bs[srow][sc0] =
            *(const short8*)(Wp + (size_t)(bn + srow) * 1024 + k0 + sc0);
        if (tid < 128)
            *(short8*)&As[srow][sc0] =
                *(const short8*)(Ain + (size_t)(bm + srow) * 1024 + k0 + sc0);
        __syncthreads();

        const short8 bf = *(const short8*)&Bs[w * 16 + l15][q * 8];
#pragma unroll
        for (int mt = 0; mt < 2; ++mt) {
            const short8 af = *(const short8*)&As[mt * 16 + l15][q * 8];
            acc[mt] = __builtin_amdgcn_mfma_f32_16x16x32_bf16(af, bf, acc[mt], 0, 0, 0);
        }
        __syncthreads();
    }

    const int col = bn + w * 16 + l15;
    if (blockIdx.y < 16) {
        // gru tile: stash biased pre-activations to LDS, then gate
#pragma unroll
        for (int mt = 0; mt < 2; ++mt) {
            const float bv = biasp[col];
#pragma unroll
            for (int r = 0; r < 4; ++r)
                CS[mt * 16 + q * 4 + r][w * 16 + l15] = acc[mt][r] + bv;
        }
        __syncthreads();
#pragma unroll
        for (int it = 0; it < 2; ++it) {
            const int o = tid + 256 * it;      // 0..511
            const int row = o >> 4;            // 0..31
            const int j16 = o & 15;
            const float r_pre = CS[row][4 * j16 + 0];
            const float z_pre = CS[row][4 * j16 + 1];
            const float ni    = CS[row][4 * j16 + 2];
            const float nh    = CS[row][4 * j16 + 3];
            const float r = 1.f / (1.f + expf(-r_pre));
            const float z = 1.f / (1.f + expf(-z_pre));
            const float n = tanhf(fmaf(r, nh, ni));
            const int b = bm + row;
            const int j = blockIdx.y * 16 + j16;
            const float hp = h[b * NH + j];
            const float hn = (1.f - z) * n + z * hp;
            h[b * NH + j] = hn;
            Aout[(size_t)b * 1024 + 768 + j] = f2bf(hn);
        }
    } else {
        // FC tile: out[b, out_step, c]
        if (out_step >= 0) {
            const int c = col - 1024;
            if (c < NC) {
                const float bv = biasp[col];
#pragma unroll
                for (int mt = 0; mt < 2; ++mt)
#pragma unroll
                    for (int r = 0; r < 4; ++r) {
                        const int row = bm + mt * 16 + q * 4 + r;
                        out[((size_t)row * NSTEPS + out_step) * NC + c] = acc[mt][r] + bv;
                    }
            }
        }
    }
}

// ---------------------------------------------------------------------------
// Attention step (no gate): sProj + scores + softmax + ctx -> Aout emb/ctx.
// 512 threads (8 waves), grid 512.  step==-1: init (h=0, also zero h/h-slot).
// ---------------------------------------------------------------------------
__global__ __launch_bounds__(512) void k_step(
    float* __restrict__ h, unsigned short* __restrict__ Aout,
    const unsigned short* __restrict__ Wsbf, const float* __restrict__ bs,
    const unsigned short* __restrict__ imgbf, const float* __restrict__ imgf,
    int use_bf, const unsigned short* __restrict__ xProjbf,
    const float* __restrict__ Ww, const float* __restrict__ bw,
    const float* __restrict__ emb, const int* __restrict__ label, int step)
{
    const int b = blockIdx.x;
    const int tid = threadIdx.x;
    const int lane = tid & 63;
    const int w = tid >> 6;

    __shared__ float hS[NH];
    __shared__ float wwS[NA];
    __shared__ float bsS[NA];
    __shared__ float spS[2][NA];
    __shared__ float vS[NT];
    __shared__ float alphaS[NT];
    __shared__ float ctxS[8][512];

    const int att_step = step + 1;
    if (tid < 256) {
        const int y = (att_step == 0) ? 0 : label[b * NSTEPS + att_step];
        Aout[(size_t)b * 1024 + tid] = f2bf(emb[y * NA + tid]);
        wwS[tid] = Ww[tid];
        bsS[tid] = bs[tid];
        if (step >= 0) {
            hS[tid] = h[b * NH + tid];
        } else {
            hS[tid] = 0.f;
            h[b * NH + tid] = 0.f;
            Aout[(size_t)b * 1024 + 768 + tid] = 0;   // bf16(0)
        }
    }
    __syncthreads();

    // ---- sProj split-K: thread (j = tid&255, half = tid>>8) ----
    {
        const int j = tid & 255, half = tid >> 8;
        float sp = 0.f;
        if (step >= 0) {
            const unsigned short* wr = Wsbf + (size_t)j * NH + half * 128;
#pragma unroll
            for (int kk = 0; kk < 16; ++kk) {
                const short8 wv = *(const short8*)(wr + kk * 8);
#pragma unroll
                for (int i = 0; i < 8; ++i)
                    sp = fmaf(hS[half * 128 + kk * 8 + i],
                              bf2f((unsigned short)wv[i]), sp);
            }
        }
        spS[half][j] = sp;
    }
    __syncthreads();

    // ---- scores: half-wave per t, lane covers 8 a's ----
    const int a0 = (lane & 31) * 8;
    float ss[8], ww[8];
#pragma unroll
    for (int i = 0; i < 8; ++i) {
        ss[i] = spS[0][a0 + i] + spS[1][a0 + i] + bsS[a0 + i];
        ww[i] = wwS[a0 + i];
    }
    const float bw0 = bw[0];
#pragma unroll 2
    for (int p = 0; p < 4; ++p) {
        const int t = w * 8 + p * 2 + (lane >> 5);
        const short8 x8 = *(const short8*)(xProjbf + ((size_t)(b * NT + t)) * NA + a0);
        float s = 0.f;
#pragma unroll
        for (int i = 0; i < 8; ++i)
            s += ww[i] * tanhf(ss[i] + bf2f((unsigned short)x8[i]));
#pragma unroll
        for (int off = 16; off > 0; off >>= 1) s += __shfl_xor(s, off);
        if ((lane & 31) == 0) vS[t] = s + bw0;
    }
    __syncthreads();

    // ---- softmax over 64 t (wave 0) ----
    if (w == 0) {
        float v = vS[lane];
        float m = v;
#pragma unroll
        for (int off = 32; off > 0; off >>= 1) m = fmaxf(m, __shfl_xor(m, off));
        float e = expf(v - m);
        float ssum = e;
#pragma unroll
        for (int off = 32; off > 0; off >>= 1) ssum += __shfl_xor(ssum, off);
        alphaS[lane] = e / ssum;
    }
    __syncthreads();

    // ---- ctx: wave covers 8 t, lane covers 8 contiguous d ----
    const int d0 = lane * 8;
    float c[8];
#pragma unroll
    for (int i = 0; i < 8; ++i) c[i] = 0.f;

    if (use_bf) {
        const unsigned short* ib = imgbf + (size_t)b * NT * ND + d0;
#pragma unroll 2
        for (int i = 0; i < 8; ++i) {
            const int t = w + 8 * i;
            const float al = alphaS[t];
            const short8 v = *(const short8*)(ib + (size_t)t * ND);
#pragma unroll
            for (int k = 0; k < 8; ++k)
                c[k] = fmaf(al, bf2f((unsigned short)v[k]), c[k]);
        }
    } else {
        const float* ib = imgf + (size_t)b * NT * ND + d0;
#pragma unroll 2
        for (int i = 0; i < 8; ++i) {
            const int t = w + 8 * i;
            const float al = alphaS[t];
            const float4 v0 = *(const float4*)(ib + (size_t)t * ND);
            const float4 v1 = *(const float4*)(ib + (size_t)t * ND + 4);
            c[0] = fmaf(al, v0.x, c[0]); c[1] = fmaf(al, v0.y, c[1]);
            c[2] = fmaf(al, v0.z, c[2]); c[3] = fmaf(al, v0.w, c[3]);
            c[4] = fmaf(al, v1.x, c[4]); c[5] = fmaf(al, v1.y, c[5]);
            c[6] = fmaf(al, v1.z, c[6]); c[7] = fmaf(al, v1.w, c[7]);
        }
    }
    *(f32x4*)&ctxS[w][d0] = (f32x4){c[0], c[1], c[2], c[3]};
    *(f32x4*)&ctxS[w][d0 + 4] = (f32x4){c[4], c[5], c[6], c[7]};
    __syncthreads();

    // final reduce across 8 waves; one d per thread
    float cx = ctxS[0][tid] + ctxS[1][tid] + ctxS[2][tid] + ctxS[3][tid]
             + ctxS[4][tid] + ctxS[5][tid] + ctxS[6][tid] + ctxS[7][tid];
    Aout[(size_t)b * 1024 + 256 + tid] = f2bf(cx);
}

// Final-step FC: out[b,25,:] = h @ Wfc.T + bfc
__global__ __launch_bounds__(128) void k_fc(
    const float* __restrict__ h, const unsigned short* __restrict__ WfcT,
    const float* __restrict__ bfc, float* __restrict__ out)
{
    const int b = blockIdx.x;
    const int j = threadIdx.x;
    __shared__ float hS[NH];
    hS[j] = h[b * NH + j];
    hS[128 + j] = h[b * NH + 128 + j];
    __syncthreads();
    if (j < NC) {
        float acc = bfc[j];
#pragma unroll 8
        for (int k = 0; k < NH; ++k)
            acc = fmaf(hS[k], bf2f(WfcT[k * NC + j]), acc);
        out[((size_t)b * NSTEPS + (NSTEPS - 1)) * NC + j] = acc;
    }
}

// ---------------------------------------------------------------------------
extern "C" void kernel_launch(void* const* d_in, const int* in_sizes, int n_in,
                              void* d_out, int out_size, void* d_ws, size_t ws_size,
                              hipStream_t stream)
{
    const float* img   = (const float*)d_in[0];
    const int*   label = (const int*)d_in[1];
    const float* Wx    = (const float*)d_in[2];
    const float* bx    = (const float*)d_in[3];
    const float* Ws    = (const float*)d_in[4];
    const float* bs    = (const float*)d_in[5];
    const float* Ww    = (const float*)d_in[6];
    const float* bw    = (const float*)d_in[7];
    const float* emb   = (const float*)d_in[8];
    const float* Wih   = (const float*)d_in[9];
    const float* bih   = (const float*)d_in[10];
    const float* Whh   = (const float*)d_in[11];
    const float* bhh   = (const float*)d_in[12];
    const float* Wfc   = (const float*)d_in[13];
    const float* bfc   = (const float*)d_in[14];
    float* out = (float*)d_out;

    float* ws = (float*)d_ws;
    float* h     = ws;                                       // 131072 f
    float* biasp = h + 131072;                               // 1280 f (1152 used)
    unsigned short* xProjbf = (unsigned short*)(biasp + 1280);   // 8388608 s
    unsigned short* A0   = xProjbf + 8388608;                // 524288 s
    unsigned short* A1   = A0 + 524288;                      // 524288 s
    unsigned short* Wp   = A1 + 524288;                      // 1179648 s
    unsigned short* Wxbf = Wp + 1179648;                     // 131072 s
    unsigned short* Wsbf = Wxbf + 131072;                    // 65536 s
    unsigned short* WfcT = Wsbf + 65536;                     // 24576 s
    unsigned short* imgbf = WfcT + 24576;                    // 16777216 s (optional)

    const size_t need_bf = (size_t)((char*)(imgbf + 16777216) - (char*)d_ws);
    const int use_bf = (ws_size >= need_bf) ? 1 : 0;

    k_prep<<<dim3(4608), dim3(256), 0, stream>>>(
        Wx, Ws, Wfc, Wih, Whh, bih, bhh, bfc,
        Wxbf, Wsbf, WfcT, Wp, biasp);

    if (use_bf)
        k_convert<<<dim3(8192), dim3(256), 0, stream>>>(img, imgbf);

    k_xproj<<<dim3((NB * NT) / 64, NA / 64), dim3(256), 0, stream>>>(
        img, imgbf, use_bf, Wxbf, bx, xProjbf);

    // init: h=0, A0 = [emb(y0), ctx0, 0]
    k_step<<<dim3(NB), dim3(512), 0, stream>>>(
        h, A0, Wsbf, bs, imgbf, img, use_bf, xProjbf,
        Ww, bw, emb, label, -1);

    for (int s = 0; s < NSTEPS; ++s) {
        unsigned short* Ain  = (s & 1) ? A1 : A0;
        unsigned short* Aout = (s & 1) ? A0 : A1;

        k_gru<<<dim3(16, 18), dim3(256), 0, stream>>>(
            Ain, Aout, Wp, biasp, h, out, s - 1);

        if (s < NSTEPS - 1)
            k_step<<<dim3(NB), dim3(512), 0, stream>>>(
                h, Aout, Wsbf, bs, imgbf, img, use_bf, xProjbf,
                Ww, bw, emb, label, s);
    }

    k_fc<<<dim3(NB), dim3(128), 0, stream>>>(h, WfcT, bfc, out);
}